// Round 1
// baseline (751.227 us; speedup 1.0000x reference)
//
#include <hip/hip_runtime.h>

typedef __attribute__((ext_vector_type(8))) short short8;
typedef __attribute__((ext_vector_type(4))) float f32x4;
typedef __attribute__((ext_vector_type(4))) unsigned short u16x4;

#define D_DIM 1024

__device__ __forceinline__ unsigned short f2bf(float f) {
  unsigned u = __builtin_bit_cast(unsigned, f);
  u += 0x7fffu + ((u >> 16) & 1u);
  return (unsigned short)(u >> 16);
}
__device__ __forceinline__ float bf2f(unsigned short b) {
  return __builtin_bit_cast(float, ((unsigned)b) << 16);
}
__device__ __forceinline__ float gelu_f(float x) {
  float i = 0.7978845608028654f * (x + 0.044715f * x * x * x);
  return 0.5f * x * (1.0f + tanhf(i));
}

__device__ __forceinline__ f32x4 mfma16(short8 a, short8 b, f32x4 c) {
  return __builtin_amdgcn_mfma_f32_16x16x32_bf16(a, b, c, 0, 0, 0);
}

// Split fp32 W[K][N] into bf16 hi/lo, transposed to [N][K] for contiguous-K staging.
__global__ __launch_bounds__(256) void prep_w_kernel(
    const float* __restrict__ W, unsigned short* __restrict__ Wth,
    unsigned short* __restrict__ Wtl) {
  __shared__ float tile[64][65];
  const int t = threadIdx.x;
  const int k0 = blockIdx.x * 64, n0 = blockIdx.y * 64;
  const size_t lbase = (size_t)blockIdx.z * D_DIM * D_DIM;
#pragma unroll
  for (int j = 0; j < 16; ++j) {
    int idx = t + 256 * j;
    int r = idx >> 6, c = idx & 63;
    tile[r][c] = W[lbase + (size_t)(k0 + r) * D_DIM + (n0 + c)];
  }
  __syncthreads();
#pragma unroll
  for (int j = 0; j < 16; ++j) {
    int idx = t + 256 * j;
    int r = idx >> 6, c = idx & 63;  // out row n0+r, col k0+c
    float f = tile[c][r];
    unsigned short hb = f2bf(f);
    unsigned short lb = f2bf(f - bf2f(hb));
    size_t oidx = lbase + (size_t)(n0 + r) * D_DIM + (k0 + c);
    Wth[oidx] = hb;
    Wtl[oidx] = lb;
  }
}

// C[M][N] = gelu(H[M][K] * W[K][N] + b), via split bf16 MFMA.
// grid: (N/128, M/128), block 256 (4 waves, each owns a 64x64 quadrant).
__global__ __launch_bounds__(256) void gemm_gelu_kernel(
    const float* __restrict__ H, const unsigned short* __restrict__ Wth,
    const unsigned short* __restrict__ Wtl, const float* __restrict__ bias,
    float* __restrict__ Hout) {
  // LDS layout [kgroup][row][8]: frag reads are 16B-aligned ds_read_b128,
  // bank pattern = 2-way (free per m136).
  __shared__ unsigned short Ah[4][128][8], Al[4][128][8];
  __shared__ unsigned short Bh[4][128][8], Bl[4][128][8];
  const int t = threadIdx.x;
  const int bn0 = blockIdx.x * 128;
  const int bm0 = blockIdx.y * 128;
  const int lane = t & 63, wid = t >> 6;
  const int wr = wid >> 1, wc = wid & 1;
  const int g = lane >> 4, r16 = lane & 15;

  f32x4 acc[4][4];
#pragma unroll
  for (int i = 0; i < 4; ++i)
#pragma unroll
    for (int j = 0; j < 4; ++j) acc[i][j] = (f32x4)0.0f;

  for (int k0 = 0; k0 < D_DIM; k0 += 32) {
    // ---- stage A: 128 rows x 32 k of fp32 H, split to hi/lo bf16
#pragma unroll
    for (int j = 0; j < 4; ++j) {
      int idx = t + 256 * j;
      int row = idx >> 3;
      int kv = (idx & 7) << 2;  // 0,4,...,28
      const float4 v =
          *(const float4*)(H + (size_t)(bm0 + row) * D_DIM + k0 + kv);
      u16x4 h4, l4;
      const float fv[4] = {v.x, v.y, v.z, v.w};
#pragma unroll
      for (int c = 0; c < 4; ++c) {
        unsigned short hb = f2bf(fv[c]);
        h4[c] = hb;
        l4[c] = f2bf(fv[c] - bf2f(hb));
      }
      *(u16x4*)&Ah[kv >> 3][row][kv & 7] = h4;
      *(u16x4*)&Al[kv >> 3][row][kv & 7] = l4;
    }
    // ---- stage B: 128 cols x 32 k from pre-split W^T (bf16), direct copy
#pragma unroll
    for (int j = 0; j < 2; ++j) {
      int idx = t + 256 * j;  // 512 tasks
      int row = idx >> 2;
      int gg = idx & 3;
      const size_t goff = (size_t)(bn0 + row) * D_DIM + k0 + gg * 8;
      *(short8*)&Bh[gg][row][0] = *(const short8*)(Wth + goff);
      *(short8*)&Bl[gg][row][0] = *(const short8*)(Wtl + goff);
    }
    __syncthreads();

    short8 afh[4], afl[4], bfh[4], bfl[4];
#pragma unroll
    for (int i = 0; i < 4; ++i) {
      int row = wr * 64 + i * 16 + r16;
      afh[i] = *(const short8*)&Ah[g][row][0];
      afl[i] = *(const short8*)&Al[g][row][0];
      int col = wc * 64 + i * 16 + r16;
      bfh[i] = *(const short8*)&Bh[g][col][0];
      bfl[i] = *(const short8*)&Bl[g][col][0];
    }
#pragma unroll
    for (int mi = 0; mi < 4; ++mi)
#pragma unroll
      for (int ni = 0; ni < 4; ++ni) {
        acc[mi][ni] = mfma16(afl[mi], bfh[ni], acc[mi][ni]);
        acc[mi][ni] = mfma16(afh[mi], bfl[ni], acc[mi][ni]);
        acc[mi][ni] = mfma16(afh[mi], bfh[ni], acc[mi][ni]);
      }
    __syncthreads();
  }

  // epilogue: bias + gelu, C/D layout col=lane&15, row=(lane>>4)*4+reg
#pragma unroll
  for (int ni = 0; ni < 4; ++ni) {
    int col = bn0 + wc * 64 + ni * 16 + r16;
    float bc = bias[col];
#pragma unroll
    for (int mi = 0; mi < 4; ++mi) {
#pragma unroll
      for (int j = 0; j < 4; ++j) {
        int row = bm0 + wr * 64 + mi * 16 + g * 4 + j;
        float v = acc[mi][ni][j] + bc;
        Hout[(size_t)row * D_DIM + col] = gelu_f(v);
      }
    }
  }
}

// Per-token ACT update: one block per token row.
__global__ __launch_bounds__(256) void act_update_kernel(
    const float* __restrict__ Hstep, const float* __restrict__ halt_w,
    const float* __restrict__ halt_b, float* __restrict__ out,
    float* __restrict__ cum, float* __restrict__ rem,
    float* __restrict__ pond, int step, int last) {
  const int tok = blockIdx.x;
  const int t = threadIdx.x;
  const float4 hv = *(const float4*)(Hstep + (size_t)tok * D_DIM + t * 4);
  const float4 wv = *(const float4*)(halt_w + t * 4);
  float part = hv.x * wv.x + hv.y * wv.y + hv.z * wv.z + hv.w * wv.w;
#pragma unroll
  for (int off = 32; off; off >>= 1) part += __shfl_down(part, off);
  __shared__ float wsum[4];
  __shared__ float wbroad;
  if ((t & 63) == 0) wsum[t >> 6] = part;
  __syncthreads();
  if (t == 0) {
    float z = wsum[0] + wsum[1] + wsum[2] + wsum[3] + halt_b[0];
    float p = 1.0f / (1.0f + expf(-z));
    float c, r, q;
    if (step == 0) {
      c = 0.0f; r = 1.0f; q = 0.0f;
    } else {
      c = cum[tok]; r = rem[tok]; q = pond[tok];
    }
    float weight;
    if (last) {
      weight = r;
    } else {
      weight = ((c + p) >= 0.99f) ? r : p;
    }
    q += weight;
    c += weight;  // contrib == weight in both branches
    r = fmaxf(1.0f - c, 0.0f);
    cum[tok] = c; rem[tok] = r; pond[tok] = q;
    wbroad = weight;
  }
  __syncthreads();
  const float w = wbroad;
  float* orow = out + (size_t)tok * D_DIM + t * 4;
  float4 o;
  if (step == 0) {
    o = make_float4(0.f, 0.f, 0.f, 0.f);
  } else {
    o = *(const float4*)orow;
  }
  o.x += w * hv.x; o.y += w * hv.y; o.z += w * hv.z; o.w += w * hv.w;
  *(float4*)orow = o;
}

__global__ __launch_bounds__(256) void ponder_reduce_kernel(
    const float* __restrict__ pond, float* __restrict__ o, int n) {
  __shared__ float sh[256];
  float a = 0.0f;
  for (int i = threadIdx.x; i < n; i += 256) a += pond[i];
  sh[threadIdx.x] = a;
  __syncthreads();
  for (int s = 128; s; s >>= 1) {
    if ((int)threadIdx.x < s) sh[threadIdx.x] += sh[threadIdx.x + s];
    __syncthreads();
  }
  if (threadIdx.x == 0) o[0] = sh[0] / (float)n;
}

extern "C" void kernel_launch(void* const* d_in, const int* in_sizes, int n_in,
                              void* d_out, int out_size, void* d_ws,
                              size_t ws_size, hipStream_t stream) {
  const float* x = (const float*)d_in[0];
  const float* layer_w = (const float*)d_in[1];
  const float* layer_b = (const float*)d_in[2];
  const float* halt_w = (const float*)d_in[3];
  const float* halt_b = (const float*)d_in[4];
  float* out = (float*)d_out;

  const int D = D_DIM;
  const int M = in_sizes[0] / D;        // 16384
  const int L = in_sizes[1] / (D * D);  // 4

  char* ws = (char*)d_ws;
  size_t off = 0;
  unsigned short* Wth = (unsigned short*)(ws + off); off += (size_t)L * D * D * 2;
  unsigned short* Wtl = (unsigned short*)(ws + off); off += (size_t)L * D * D * 2;
  float* hA = (float*)(ws + off); off += (size_t)M * D * 4;
  float* hB = (float*)(ws + off); off += (size_t)M * D * 4;
  float* cum = (float*)(ws + off); off += (size_t)M * 4;
  float* rem = (float*)(ws + off); off += (size_t)M * 4;
  float* pond = (float*)(ws + off); off += (size_t)M * 4;
  float* pcost = out + (size_t)M * D;

  prep_w_kernel<<<dim3(D / 64, D / 64, L), 256, 0, stream>>>(layer_w, Wth, Wtl);

  const float* cur = x;
  for (int s = 0; s < L; ++s) {
    float* nxt = (s & 1) ? hB : hA;
    gemm_gelu_kernel<<<dim3(D / 128, M / 128), 256, 0, stream>>>(
        cur, Wth + (size_t)s * D * D, Wtl + (size_t)s * D * D,
        layer_b + (size_t)s * D, nxt);
    act_update_kernel<<<M, 256, 0, stream>>>(nxt, halt_w, halt_b, out, cum,
                                             rem, pond, s, (s == L - 1) ? 1 : 0);
    cur = nxt;
  }
  ponder_reduce_kernel<<<1, 256, 0, stream>>>(pond, pcost, M);
}